// Round 3
// baseline (1367.739 us; speedup 1.0000x reference)
//
#include <hip/hip_runtime.h>
#include <stdint.h>

#define NH 4
#define HD 64
#define DM 256
#define BB 16
#define PLEN 512
#define GLEN 16384
#define ML 16
#define NCH_MAX 32

typedef __attribute__((ext_vector_type(8))) short bf16x8;
typedef __attribute__((ext_vector_type(4))) short s16x4;
typedef __attribute__((ext_vector_type(4))) float f32x4;
struct fl4 { float x, y, z, w; };

#define MFMA16(a, b, c) __builtin_amdgcn_mfma_f32_16x16x32_bf16((a), (b), (c), 0, 0, 0)

__device__ __forceinline__ float bf2f(short x) {
  union { unsigned u; float f; } v;
  v.u = ((unsigned)(unsigned short)x) << 16;
  return v.f;
}
__device__ __forceinline__ short f2bf(float x) {
  union { float f; unsigned u; } v;
  v.f = x;
  unsigned u = v.u;
  u += 0x7fffu + ((u >> 16) & 1u);  // RNE
  return (short)(u >> 16);
}

// ---------------- dtype detection: fp32-as-bf16 even shorts are wild ----------------
__global__ void detect_dtype(const short* __restrict__ pattern, int* __restrict__ flag) {
  int t = threadIdx.x;
  int bad = 0;
  for (int i = t; i < 4096; i += 256) {
    float v = bf2f(pattern[2 * i]);
    if (!(fabsf(v) < 1e10f)) bad++;  // catches huge AND NaN
  }
  __shared__ int cnt;
  if (t == 0) cnt = 0;
  __syncthreads();
  if (bad) atomicAdd(&cnt, bad);
  __syncthreads();
  if (t == 0) flag[0] = (cnt > 8) ? 1 : 0;  // 1 = inputs are float32
}

// ---------------- weight transpose (+dtype convert): W[K][256] -> WT[256][K] bf16 ----------------
struct WTArgs {
  const void* src[10];
  short* dst[10];
  int rows[10];
};

__global__ void transpose_w(WTArgs a, const int* __restrict__ flag) {
  int mid = blockIdx.z;
  int K = a.rows[mid];
  int tk = blockIdx.x, tn = blockIdx.y;
  if (tk * 32 >= K) return;  // block-uniform
  int isf = flag[0];
  __shared__ short tile[32][33];
  const short* src = (const short*)a.src[mid];
  const float* srcf = (const float*)a.src[mid];
  short* dst = a.dst[mid];
  int tx = threadIdx.x, ty = threadIdx.y;  // 32 x 8
  for (int i = 0; i < 32; i += 8) {
    size_t idx = (size_t)(tk * 32 + ty + i) * 256 + tn * 32 + tx;
    tile[ty + i][tx] = isf ? f2bf(srcf[idx]) : src[idx];
  }
  __syncthreads();
  for (int i = 0; i < 32; i += 8)
    dst[(size_t)(tn * 32 + ty + i) * K + tk * 32 + tx] = tile[tx][ty + i];
}

// ---------------- bias convert ----------------
__global__ void conv_bias(const void* p_bg, const void* g_bg, short* out,
                          const int* __restrict__ flag) {
  int t = threadIdx.x;
  int isf = flag[0];
  out[t] = isf ? f2bf(((const float*)p_bg)[t]) : ((const short*)p_bg)[t];
  out[256 + t] = isf ? f2bf(((const float*)g_bg)[t]) : ((const short*)g_bg)[t];
}

// ---------------- mean pool (init_mem) + first q-projection ----------------
__global__ __launch_bounds__(256) void meanpool_q0(
    const void* __restrict__ graph, const void* __restrict__ Wq,
    float* __restrict__ mem, short* __restrict__ hq, const int* __restrict__ flag) {
  int b = blockIdx.x >> 4, m = blockIdx.x & 15;
  int t = threadIdx.x;
  int isf = flag[0];
  size_t goff = ((size_t)b * GLEN + (size_t)m * 1024) * DM;
  int cp = t & 127, rh = t >> 7;  // col-pair, row-half
  float s0 = 0.f, s1 = 0.f;
  if (isf) {
    const float* gb = (const float*)graph + goff;
    for (int r = rh; r < 1024; r += 2) {
      const float* p = gb + (size_t)r * DM + cp * 2;
      s0 += p[0];
      s1 += p[1];
    }
  } else {
    const short* gb = (const short*)graph + goff;
    for (int r = rh; r < 1024; r += 2) {
      unsigned u = *(const unsigned*)(gb + (size_t)r * DM + cp * 2);
      s0 += bf2f((short)(u & 0xffffu));
      s1 += bf2f((short)(u >> 16));
    }
  }
  __shared__ float part[2][256];
  part[rh][cp * 2] = s0;
  part[rh][cp * 2 + 1] = s1;
  __syncthreads();
  __shared__ float memrow[256];
  float v = (part[0][t] + part[1][t]) * (1.0f / 1024.0f);
  memrow[t] = bf2f(f2bf(v));  // bf16-rounded copy (matches MFMA path numerics)
  mem[((size_t)b * ML + m) * DM + t] = v;
  __syncthreads();
  float acc = 0.f;
  if (isf) {
    const float* wf = (const float*)Wq;
    for (int k = 0; k < 256; k++)
      acc += memrow[k] * bf2f(f2bf(wf[(size_t)k * 256 + t]));
  } else {
    const short* ws = (const short*)Wq;
    for (int k = 0; k < 256; k++)
      acc += memrow[k] * bf2f(ws[(size_t)k * 256 + t]);
  }
  hq[((size_t)b * ML + m) * DM + t] = f2bf(acc);
}

// ---------------- K/V projection: X(rows,256) @ W -> K row-major / V transposed ----------------
__global__ __launch_bounds__(512, 2) void proj_kv(
    const void* __restrict__ Xv, const short* __restrict__ WkT,
    const short* __restrict__ WvT, short* __restrict__ Kout,
    short* __restrict__ Vt, int L, const int* __restrict__ flag) {
  __shared__ __align__(16) short Xs[128 * 32];  // [row][k], 64B rows
  __shared__ __align__(16) short Ws[256 * 32];  // [n][k],  64B rows
  const short* WT = blockIdx.y ? WvT : WkT;
  int isf = flag[0];
  int row0 = blockIdx.x * 128;
  int t = threadIdx.x;
  int wave = t >> 6, lane = t & 63, quad = lane >> 4, l16 = lane & 15;
  int wrow = (wave >> 2) * 64, wcol = (wave & 3) * 64;
  int tr = t >> 2, tc = t & 3;  // staging: thread -> (row, 8-col chunk)
  f32x4 z = {0.f, 0.f, 0.f, 0.f};
  f32x4 acc[4][4];
#pragma unroll
  for (int i = 0; i < 4; i++)
#pragma unroll
    for (int j = 0; j < 4; j++) acc[i][j] = z;

  for (int kk = 0; kk < 8; kk++) {
    bf16x8 x0;
    if (isf) {
      const float* Xf = (const float*)Xv + (size_t)(row0 + tr) * DM + kk * 32 + tc * 8;
      fl4 u0 = *(const fl4*)Xf;
      fl4 u1 = *(const fl4*)(Xf + 4);
      x0[0] = f2bf(u0.x); x0[1] = f2bf(u0.y); x0[2] = f2bf(u0.z); x0[3] = f2bf(u0.w);
      x0[4] = f2bf(u1.x); x0[5] = f2bf(u1.y); x0[6] = f2bf(u1.z); x0[7] = f2bf(u1.w);
    } else {
      x0 = *(const bf16x8*)((const short*)Xv + (size_t)(row0 + tr) * DM + kk * 32 + tc * 8);
    }
    bf16x8 w0 = *(const bf16x8*)(WT + (size_t)tr * DM + kk * 32 + tc * 8);
    bf16x8 w1 = *(const bf16x8*)(WT + (size_t)(tr + 128) * DM + kk * 32 + tc * 8);
    *(bf16x8*)(Xs + tr * 32 + tc * 8) = x0;
    *(bf16x8*)(Ws + tr * 32 + tc * 8) = w0;
    *(bf16x8*)(Ws + (tr + 128) * 32 + tc * 8) = w1;
    __syncthreads();
    bf16x8 af[4], bfr[4];
#pragma unroll
    for (int rt = 0; rt < 4; rt++)
      af[rt] = *(const bf16x8*)(Xs + (wrow + rt * 16 + l16) * 32 + quad * 8);
#pragma unroll
    for (int ct = 0; ct < 4; ct++)
      bfr[ct] = *(const bf16x8*)(Ws + (wcol + ct * 16 + l16) * 32 + quad * 8);
#pragma unroll
    for (int rt = 0; rt < 4; rt++)
#pragma unroll
      for (int ct = 0; ct < 4; ct++)
        acc[rt][ct] = MFMA16(af[rt], bfr[ct], acc[rt][ct]);
    __syncthreads();
  }
  if (blockIdx.y == 0) {
#pragma unroll
    for (int rt = 0; rt < 4; rt++)
#pragma unroll
      for (int ct = 0; ct < 4; ct++) {
        int col = wcol + ct * 16 + l16;
#pragma unroll
        for (int r = 0; r < 4; r++) {
          int row = row0 + wrow + rt * 16 + quad * 4 + r;
          Kout[(size_t)row * DM + col] = f2bf(acc[rt][ct][r]);
        }
      }
  } else {
#pragma unroll
    for (int rt = 0; rt < 4; rt++) {
      int gr = row0 + wrow + rt * 16 + quad * 4;
      int bb = gr / L, j = gr % L;
#pragma unroll
      for (int ct = 0; ct < 4; ct++) {
        int c = wcol + ct * 16 + l16;
        s16x4 pv;
#pragma unroll
        for (int r = 0; r < 4; r++) pv[r] = f2bf(acc[rt][ct][r]);
        *(s16x4*)(Vt + ((size_t)bb * DM + c) * L + j) = pv;
      }
    }
  }
}

// ---------------- flash attention partials (one wave = one head) ----------------
__global__ __launch_bounds__(256, 4) void flash_partial(
    const short* __restrict__ hq, const short* __restrict__ Kb,
    const short* __restrict__ Vt, const int* __restrict__ mask,
    float* __restrict__ pm, float* __restrict__ pl, float* __restrict__ pO,
    int L, int NCH) {
  int ch = blockIdx.x, b = blockIdx.y;
  int C = L / NCH;
  int t = threadIdx.x, wave = t >> 6, lane = t & 63, quad = lane >> 4, l16 = lane & 15;
  __shared__ __align__(16) short Plds[4][512];  // per-wave P tile: [q][32 keys]
  short* myP = &Plds[wave][0];
  const short* qbase = hq + ((size_t)b * ML + l16) * DM + wave * HD;
  bf16x8 aq0 = *(const bf16x8*)(qbase + quad * 8);
  bf16x8 aq1 = *(const bf16x8*)(qbase + 32 + quad * 8);
  f32x4 z = {0.f, 0.f, 0.f, 0.f};
  float m_run[4], l_run[4];
  f32x4 O[4];
#pragma unroll
  for (int r = 0; r < 4; r++) { m_run[r] = -1e30f; l_run[r] = 0.f; }
#pragma unroll
  for (int d = 0; d < 4; d++) O[d] = z;
  int j0 = ch * C;
  const float L2E = 1.44269504f;
  for (int jt = 0; jt < C; jt += 32) {
    f32x4 S[2];
#pragma unroll
    for (int tt = 0; tt < 2; tt++) {
      int j = j0 + jt + tt * 16 + l16;
      const short* kb = Kb + ((size_t)b * L + j) * DM + wave * HD;
      bf16x8 b0 = *(const bf16x8*)(kb + quad * 8);
      bf16x8 b1 = *(const bf16x8*)(kb + 32 + quad * 8);
      f32x4 s = MFMA16(aq0, b0, z);
      s = MFMA16(aq1, b1, s);
      int mk = mask[(size_t)b * L + j];
#pragma unroll
      for (int r = 0; r < 4; r++)
        S[tt][r] = mk ? s[r] * 0.125f : -1e30f;
    }
    float p[2][4], alpha[4];
#pragma unroll
    for (int r = 0; r < 4; r++) {
      float v = fmaxf(S[0][r], S[1][r]);
      v = fmaxf(v, __shfl_xor(v, 1, 16));
      v = fmaxf(v, __shfl_xor(v, 2, 16));
      v = fmaxf(v, __shfl_xor(v, 4, 16));
      v = fmaxf(v, __shfl_xor(v, 8, 16));
      float nm = fmaxf(m_run[r], v);
      alpha[r] = exp2f((m_run[r] - nm) * L2E);
      m_run[r] = nm;
      p[0][r] = exp2f((S[0][r] - nm) * L2E);
      p[1][r] = exp2f((S[1][r] - nm) * L2E);
      float ps = p[0][r] + p[1][r];
      ps += __shfl_xor(ps, 1, 16);
      ps += __shfl_xor(ps, 2, 16);
      ps += __shfl_xor(ps, 4, 16);
      ps += __shfl_xor(ps, 8, 16);
      l_run[r] = l_run[r] * alpha[r] + ps;
    }
#pragma unroll
    for (int d = 0; d < 4; d++)
#pragma unroll
      for (int r = 0; r < 4; r++) O[d][r] *= alpha[r];
#pragma unroll
    for (int tt = 0; tt < 2; tt++)
#pragma unroll
      for (int r = 0; r < 4; r++)
        myP[(quad * 4 + r) * 32 + tt * 16 + l16] = f2bf(p[tt][r]);
    __syncthreads();  // P visible (uniform trip count)
    bf16x8 ap = *(const bf16x8*)(myP + l16 * 32 + quad * 8);
#pragma unroll
    for (int d = 0; d < 4; d++) {
      const short* vb = Vt + ((size_t)b * DM + wave * HD + d * 16 + l16) * L + j0 + jt + quad * 8;
      bf16x8 bv = *(const bf16x8*)vb;
      O[d] = MFMA16(ap, bv, O[d]);
    }
    __syncthreads();  // protect P tile
  }
  size_t base = (((size_t)b * NCH + ch) * NH + wave) * ML;
  if (l16 == 0) {
#pragma unroll
    for (int r = 0; r < 4; r++) {
      pm[base + quad * 4 + r] = m_run[r];
      pl[base + quad * 4 + r] = l_run[r];
    }
  }
#pragma unroll
  for (int d = 0; d < 4; d++)
#pragma unroll
    for (int r = 0; r < 4; r++)
      pO[(base + quad * 4 + r) * 64 + d * 16 + l16] = O[d][r];
}

// ---------------- reduce partials + Wo + gate + (next Wq | final out), per batch ----------------
__global__ __launch_bounds__(256, 2) void epilogue(
    const float* __restrict__ pm, const float* __restrict__ pl,
    const float* __restrict__ pO, int NCH,
    float* __restrict__ mem, const short* __restrict__ WoT,
    const short* __restrict__ WgT, const short* __restrict__ bg,
    const short* __restrict__ WqT, short* __restrict__ hq,
    void* __restrict__ outb, const int* __restrict__ flag) {
  int b = blockIdx.x, t = threadIdx.x;
  int isf = flag[0];
  __shared__ float w_lds[NCH_MAX * 64];
  __shared__ float invL[64];
  __shared__ __align__(16) short vec_bf[ML * DM];
  __shared__ __align__(16) short mem_bf[ML * DM];
  __shared__ __align__(16) short attn_bf[ML * DM];
  __shared__ float attn_f[ML * DM];
  __shared__ __align__(16) short memn_bf[ML * DM];

  for (int idx = t; idx < ML * DM; idx += 256)
    mem_bf[idx] = f2bf(mem[(size_t)b * ML * DM + idx]);
  if (t < 64) {  // t = n*16 + i
    size_t base = (size_t)b * NCH * NH * ML + t;
    float M = -1e30f;
    for (int ch = 0; ch < NCH; ch++)
      M = fmaxf(M, pm[base + (size_t)ch * NH * ML]);
    float Ls = 0.f;
    for (int ch = 0; ch < NCH; ch++) {
      float w = exp2f((pm[base + (size_t)ch * NH * ML] - M) * 1.44269504f);
      w_lds[ch * 64 + t] = w;
      Ls += w * pl[base + (size_t)ch * NH * ML];
    }
    invL[t] = 1.0f / Ls;
  }
  __syncthreads();
  {
    int n = t >> 6, d = t & 63;
    for (int i = 0; i < 16; i++) {
      size_t pb = ((size_t)b * NCH * NH * ML + n * ML + i) * 64 + d;
      float o = 0.f;
      for (int ch = 0; ch < NCH; ch++)
        o += w_lds[ch * 64 + n * 16 + i] * pO[pb + (size_t)ch * NH * ML * 64];
      vec_bf[i * DM + n * 64 + d] = f2bf(o * invL[n * 16 + i]);
    }
  }
  __syncthreads();
  int wave = t >> 6, lane = t & 63, quad = lane >> 4, l16 = lane & 15;
  f32x4 z = {0.f, 0.f, 0.f, 0.f};
  f32x4 acc[4];
#pragma unroll
  for (int c = 0; c < 4; c++) acc[c] = z;
#pragma unroll
  for (int kk = 0; kk < 8; kk++) {
    bf16x8 a = *(const bf16x8*)(vec_bf + l16 * DM + kk * 32 + quad * 8);
#pragma unroll
    for (int ct = 0; ct < 4; ct++) {
      const short* wb = WoT + (size_t)(wave * 64 + ct * 16 + l16) * DM + kk * 32 + quad * 8;
      acc[ct] = MFMA16(a, *(const bf16x8*)wb, acc[ct]);
    }
  }
#pragma unroll
  for (int ct = 0; ct < 4; ct++)
#pragma unroll
    for (int r = 0; r < 4; r++) {
      int row = quad * 4 + r, col = wave * 64 + ct * 16 + l16;
      attn_f[row * DM + col] = acc[ct][r];
      attn_bf[row * DM + col] = f2bf(acc[ct][r]);
    }
  __syncthreads();
  f32x4 g[4];
#pragma unroll
  for (int c = 0; c < 4; c++) g[c] = z;
#pragma unroll
  for (int kk = 0; kk < 16; kk++) {
    bf16x8 a = (kk < 8)
        ? *(const bf16x8*)(mem_bf + l16 * DM + kk * 32 + quad * 8)
        : *(const bf16x8*)(attn_bf + l16 * DM + (kk - 8) * 32 + quad * 8);
#pragma unroll
    for (int ct = 0; ct < 4; ct++) {
      const short* wb = WgT + (size_t)(wave * 64 + ct * 16 + l16) * 512 + kk * 32 + quad * 8;
      g[ct] = MFMA16(a, *(const bf16x8*)wb, g[ct]);
    }
  }
#pragma unroll
  for (int ct = 0; ct < 4; ct++)
#pragma unroll
    for (int r = 0; r < 4; r++) {
      int row = quad * 4 + r, col = wave * 64 + ct * 16 + l16;
      float x = g[ct][r] + bf2f(bg[col]);
      float gg = 1.0f / (1.0f + exp2f(-x * 1.44269504f));
      float old = mem[(size_t)b * ML * DM + row * DM + col];
      float mn = gg * old + (1.0f - gg) * attn_f[row * DM + col];
      mem[(size_t)b * ML * DM + row * DM + col] = mn;
      memn_bf[row * DM + col] = f2bf(mn);
      if (outb) {
        size_t oi = (size_t)b * ML * DM + row * DM + col;
        if (isf) ((float*)outb)[oi] = mn;
        else ((short*)outb)[oi] = f2bf(mn);
      }
    }
  __syncthreads();
  if (WqT) {
    f32x4 h[4];
#pragma unroll
    for (int c = 0; c < 4; c++) h[c] = z;
#pragma unroll
    for (int kk = 0; kk < 8; kk++) {
      bf16x8 a = *(const bf16x8*)(memn_bf + l16 * DM + kk * 32 + quad * 8);
#pragma unroll
      for (int ct = 0; ct < 4; ct++) {
        const short* wb = WqT + (size_t)(wave * 64 + ct * 16 + l16) * DM + kk * 32 + quad * 8;
        h[ct] = MFMA16(a, *(const bf16x8*)wb, h[ct]);
      }
    }
#pragma unroll
    for (int ct = 0; ct < 4; ct++)
#pragma unroll
      for (int r = 0; r < 4; r++)
        hq[(size_t)b * ML * DM + (quad * 4 + r) * DM + wave * 64 + ct * 16 + l16] = f2bf(h[ct][r]);
  }
}

// ---------------- launch ----------------
extern "C" void kernel_launch(void* const* d_in, const int* in_sizes, int n_in,
                              void* d_out, int out_size, void* d_ws, size_t ws_size,
                              hipStream_t stream) {
  const void* pattern = d_in[0];
  const void* graph = d_in[1];
  const int* pmask = (const int*)d_in[2];
  const int* gmask = (const int*)d_in[3];

  char* ws = (char*)d_ws;
  size_t off = 0;
  auto alloc = [&](size_t bytes) {
    void* p = ws + off;
    off = (off + bytes + 255) & ~(size_t)255;
    return p;
  };
  int* flag = (int*)alloc(4);
  // WT order: 0 pWqT 1 pWkT 2 pWvT 3 pWoT 4 pWgT 5 gWqT 6 gWkT 7 gWvT 8 gWoT 9 gWgT
  int rows[10] = {256, 256, 256, 256, 512, 256, 256, 256, 256, 512};
  int srcidx[10] = {4, 5, 6, 7, 8, 10, 11, 12, 13, 14};
  short* WT[10];
  for (int i = 0; i < 10; i++) WT[i] = (short*)alloc((size_t)rows[i] * 256 * 2);
  short* bgc = (short*)alloc(512 * 2);  // [p_bg(256), g_bg(256)]
  short* Kp = (short*)alloc((size_t)BB * PLEN * DM * 2);
  short* Vpt = (short*)alloc((size_t)BB * PLEN * DM * 2);
  short* Kg = (short*)alloc((size_t)BB * GLEN * DM * 2);
  short* Vgt = (short*)alloc((size_t)BB * GLEN * DM * 2);
  short* hq = (short*)alloc((size_t)BB * ML * DM * 2);
  float* memf = (float*)alloc((size_t)BB * ML * DM * 4);
  float* pm = (float*)alloc((size_t)BB * NCH_MAX * NH * ML * 4);
  float* pl = (float*)alloc((size_t)BB * NCH_MAX * NH * ML * 4);
  float* pO = (float*)alloc((size_t)BB * NCH_MAX * NH * ML * 64 * 4);
  if (off > ws_size) return;  // ws too small: output stays zero -> diagnostic signal

  detect_dtype<<<dim3(1), dim3(256), 0, stream>>>((const short*)pattern, flag);

  WTArgs wa;
  for (int i = 0; i < 10; i++) {
    wa.src[i] = d_in[srcidx[i]];
    wa.dst[i] = WT[i];
    wa.rows[i] = rows[i];
  }
  transpose_w<<<dim3(16, 8, 10), dim3(32, 8), 0, stream>>>(wa, flag);
  conv_bias<<<dim3(1), dim3(256), 0, stream>>>(d_in[9], d_in[15], bgc, flag);
  meanpool_q0<<<dim3(BB * ML), dim3(256), 0, stream>>>(graph, d_in[4], memf, hq, flag);
  proj_kv<<<dim3(BB * PLEN / 128, 2), dim3(512), 0, stream>>>(pattern, WT[1], WT[2], Kp, Vpt, PLEN, flag);
  proj_kv<<<dim3(BB * GLEN / 128, 2), dim3(512), 0, stream>>>(graph, WT[6], WT[7], Kg, Vgt, GLEN, flag);

  for (int s = 0; s < 3; s++) {
    // pattern attention
    flash_partial<<<dim3(8, BB), dim3(256), 0, stream>>>(hq, Kp, Vpt, pmask, pm, pl, pO, PLEN, 8);
    epilogue<<<dim3(BB), dim3(256), 0, stream>>>(pm, pl, pO, 8, memf, WT[3], WT[4], bgc,
                                                 (const short*)WT[5], hq, (void*)nullptr, flag);
    // graph attention
    bool last = (s == 2);
    flash_partial<<<dim3(32, BB), dim3(256), 0, stream>>>(hq, Kg, Vgt, gmask, pm, pl, pO, GLEN, 32);
    epilogue<<<dim3(BB), dim3(256), 0, stream>>>(pm, pl, pO, 32, memf, WT[8], WT[9], bgc + 256,
                                                 last ? (const short*)nullptr : (const short*)WT[0],
                                                 hq, last ? d_out : (void*)nullptr, flag);
  }
}

// Round 4
// 1198.621 us; speedup vs baseline: 1.1411x; 1.1411x over previous
//
#include <hip/hip_runtime.h>
#include <stdint.h>

#define NH 4
#define HD 64
#define DM 256
#define BB 16
#define PLEN 512
#define GLEN 16384
#define ML 16
#define NCH_MAX 32

typedef __attribute__((ext_vector_type(8))) short bf16x8;
typedef __attribute__((ext_vector_type(4))) short s16x4;
typedef __attribute__((ext_vector_type(4))) float f32x4;
struct fl4 { float x, y, z, w; };

#define MFMA16(a, b, c) __builtin_amdgcn_mfma_f32_16x16x32_bf16((a), (b), (c), 0, 0, 0)

__device__ __forceinline__ float bf2f(short x) {
  union { unsigned u; float f; } v;
  v.u = ((unsigned)(unsigned short)x) << 16;
  return v.f;
}
__device__ __forceinline__ short f2bf(float x) {
  union { float f; unsigned u; } v;
  v.f = x;
  unsigned u = v.u;
  u += 0x7fffu + ((u >> 16) & 1u);  // RNE
  return (short)(u >> 16);
}

// ---------------- dtype detection: fp32-as-bf16 even shorts are wild ----------------
__global__ void detect_dtype(const short* __restrict__ pattern, int* __restrict__ flag) {
  int t = threadIdx.x;
  int bad = 0;
  for (int i = t; i < 4096; i += 256) {
    float v = bf2f(pattern[2 * i]);
    if (!(fabsf(v) < 1e10f)) bad++;  // catches huge AND NaN
  }
  __shared__ int cnt;
  if (t == 0) cnt = 0;
  __syncthreads();
  if (bad) atomicAdd(&cnt, bad);
  __syncthreads();
  if (t == 0) flag[0] = (cnt > 8) ? 1 : 0;  // 1 = inputs are float32
}

// ---------------- input convert fp32->bf16 (+column partial sums for meanpool) ----------------
// One block = 128 rows x 256 cols. do_sum: emit per-block column sums.
__global__ __launch_bounds__(256) void convert_sum(
    const void* __restrict__ src, short* __restrict__ dst,
    float* __restrict__ partials, const int* __restrict__ flag, int do_sum) {
  int isf = flag[0];
  int t = threadIdx.x;
  int r4 = t >> 6, c4 = (t & 63) * 4;
  size_t row0 = (size_t)blockIdx.x * 128;
  float s0 = 0.f, s1 = 0.f, s2 = 0.f, s3 = 0.f;
  if (isf) {
    const float* sf = (const float*)src;
    for (int it = 0; it < 32; it++) {
      size_t row = row0 + it * 4 + r4;
      fl4 v = *(const fl4*)(sf + row * DM + c4);
      s0 += v.x; s1 += v.y; s2 += v.z; s3 += v.w;
      s16x4 o;
      o[0] = f2bf(v.x); o[1] = f2bf(v.y); o[2] = f2bf(v.z); o[3] = f2bf(v.w);
      *(s16x4*)(dst + row * DM + c4) = o;
    }
  } else {
    const short* sb = (const short*)src;
    for (int it = 0; it < 32; it++) {
      size_t row = row0 + it * 4 + r4;
      s16x4 v = *(const s16x4*)(sb + row * DM + c4);
      s0 += bf2f(v[0]); s1 += bf2f(v[1]); s2 += bf2f(v[2]); s3 += bf2f(v[3]);
      *(s16x4*)(dst + row * DM + c4) = v;
    }
  }
  if (!do_sum) return;
  __shared__ float part[4][256];
  part[r4][c4] = s0;
  part[r4][c4 + 1] = s1;
  part[r4][c4 + 2] = s2;
  part[r4][c4 + 3] = s3;
  __syncthreads();
  partials[(size_t)blockIdx.x * 256 + t] =
      part[0][t] + part[1][t] + part[2][t] + part[3][t];
}

// ---------------- finalize mean + first q-projection ----------------
__global__ __launch_bounds__(256) void finalize_q0(
    const float* __restrict__ partials, const void* __restrict__ Wq,
    float* __restrict__ mem, short* __restrict__ hq, const int* __restrict__ flag) {
  int b = blockIdx.x >> 4, m = blockIdx.x & 15;
  int t = threadIdx.x;
  int isf = flag[0];
  int p0 = b * 128 + m * 8;  // first partial-block of this (b,m) segment
  float s = 0.f;
#pragma unroll
  for (int i = 0; i < 8; i++) s += partials[(size_t)(p0 + i) * 256 + t];
  float v = s * (1.0f / 1024.0f);
  __shared__ float memrow[256];
  memrow[t] = bf2f(f2bf(v));  // bf16-rounded copy (matches MFMA path numerics)
  mem[((size_t)b * ML + m) * DM + t] = v;
  __syncthreads();
  float acc = 0.f;
  if (isf) {
    const float* wf = (const float*)Wq;
    for (int k = 0; k < 256; k++)
      acc += memrow[k] * bf2f(f2bf(wf[(size_t)k * 256 + t]));
  } else {
    const short* wsp = (const short*)Wq;
    for (int k = 0; k < 256; k++)
      acc += memrow[k] * bf2f(wsp[(size_t)k * 256 + t]);
  }
  hq[((size_t)b * ML + m) * DM + t] = f2bf(acc);
}

// ---------------- weight transpose (+dtype convert): W[K][256] -> WT[256][K] bf16 ----------------
struct WTArgs {
  const void* src[10];
  short* dst[10];
  int rows[10];
};

__global__ void transpose_w(WTArgs a, const int* __restrict__ flag) {
  int mid = blockIdx.z;
  int K = a.rows[mid];
  int tk = blockIdx.x, tn = blockIdx.y;
  if (tk * 32 >= K) return;  // block-uniform
  int isf = flag[0];
  __shared__ short tile[32][33];
  const short* src = (const short*)a.src[mid];
  const float* srcf = (const float*)a.src[mid];
  short* dst = a.dst[mid];
  int tx = threadIdx.x, ty = threadIdx.y;  // 32 x 8
  for (int i = 0; i < 32; i += 8) {
    size_t idx = (size_t)(tk * 32 + ty + i) * 256 + tn * 32 + tx;
    tile[ty + i][tx] = isf ? f2bf(srcf[idx]) : src[idx];
  }
  __syncthreads();
  for (int i = 0; i < 32; i += 8)
    dst[(size_t)(tn * 32 + ty + i) * K + tk * 32 + tx] = tile[tx][ty + i];
}

// ---------------- bias convert ----------------
__global__ void conv_bias(const void* p_bg, const void* g_bg, short* out,
                          const int* __restrict__ flag) {
  int t = threadIdx.x;
  int isf = flag[0];
  out[t] = isf ? f2bf(((const float*)p_bg)[t]) : ((const short*)p_bg)[t];
  out[256 + t] = isf ? f2bf(((const float*)g_bg)[t]) : ((const short*)g_bg)[t];
}

// ---------------- K/V projection: X(rows,256) bf16 @ W -> K row-major / V transposed ----------------
__global__ __launch_bounds__(512, 2) void proj_kv(
    const short* __restrict__ X, const short* __restrict__ WkT,
    const short* __restrict__ WvT, short* __restrict__ Kout,
    short* __restrict__ Vt, int L) {
  __shared__ __align__(16) short Xs[128 * 32];  // [row][k], 64B rows
  __shared__ __align__(16) short Ws[256 * 32];  // [n][k],  64B rows
  const short* WT = blockIdx.y ? WvT : WkT;
  int row0 = blockIdx.x * 128;
  int t = threadIdx.x;
  int wave = t >> 6, lane = t & 63, quad = lane >> 4, l16 = lane & 15;
  int wrow = (wave >> 2) * 64, wcol = (wave & 3) * 64;
  int tr = t >> 2, tc = t & 3;  // staging: thread -> (row, 8-col chunk)
  f32x4 z = {0.f, 0.f, 0.f, 0.f};
  f32x4 acc[4][4];
#pragma unroll
  for (int i = 0; i < 4; i++)
#pragma unroll
    for (int j = 0; j < 4; j++) acc[i][j] = z;

  for (int kk = 0; kk < 8; kk++) {
    bf16x8 x0 = *(const bf16x8*)(X + (size_t)(row0 + tr) * DM + kk * 32 + tc * 8);
    bf16x8 w0 = *(const bf16x8*)(WT + (size_t)tr * DM + kk * 32 + tc * 8);
    bf16x8 w1 = *(const bf16x8*)(WT + (size_t)(tr + 128) * DM + kk * 32 + tc * 8);
    *(bf16x8*)(Xs + tr * 32 + tc * 8) = x0;
    *(bf16x8*)(Ws + tr * 32 + tc * 8) = w0;
    *(bf16x8*)(Ws + (tr + 128) * 32 + tc * 8) = w1;
    __syncthreads();
    bf16x8 af[4], bfr[4];
#pragma unroll
    for (int rt = 0; rt < 4; rt++)
      af[rt] = *(const bf16x8*)(Xs + (wrow + rt * 16 + l16) * 32 + quad * 8);
#pragma unroll
    for (int ct = 0; ct < 4; ct++)
      bfr[ct] = *(const bf16x8*)(Ws + (wcol + ct * 16 + l16) * 32 + quad * 8);
#pragma unroll
    for (int rt = 0; rt < 4; rt++)
#pragma unroll
      for (int ct = 0; ct < 4; ct++)
        acc[rt][ct] = MFMA16(af[rt], bfr[ct], acc[rt][ct]);
    __syncthreads();
  }
  if (blockIdx.y == 0) {
#pragma unroll
    for (int rt = 0; rt < 4; rt++)
#pragma unroll
      for (int ct = 0; ct < 4; ct++) {
        int col = wcol + ct * 16 + l16;
#pragma unroll
        for (int r = 0; r < 4; r++) {
          int row = row0 + wrow + rt * 16 + quad * 4 + r;
          Kout[(size_t)row * DM + col] = f2bf(acc[rt][ct][r]);
        }
      }
  } else {
#pragma unroll
    for (int rt = 0; rt < 4; rt++) {
      int gr = row0 + wrow + rt * 16 + quad * 4;
      int bb = gr / L, j = gr % L;
#pragma unroll
      for (int ct = 0; ct < 4; ct++) {
        int c = wcol + ct * 16 + l16;
        s16x4 pv;
#pragma unroll
        for (int r = 0; r < 4; r++) pv[r] = f2bf(acc[rt][ct][r]);
        *(s16x4*)(Vt + ((size_t)bb * DM + c) * L + j) = pv;
      }
    }
  }
}

// ---------------- flash attention partials (one wave = one head) ----------------
__global__ __launch_bounds__(256, 4) void flash_partial(
    const short* __restrict__ hq, const short* __restrict__ Kb,
    const short* __restrict__ Vt, const int* __restrict__ mask,
    float* __restrict__ pm, float* __restrict__ pl, float* __restrict__ pO,
    int L, int NCH) {
  int ch = blockIdx.x, b = blockIdx.y;
  int C = L / NCH;
  int t = threadIdx.x, wave = t >> 6, lane = t & 63, quad = lane >> 4, l16 = lane & 15;
  __shared__ __align__(16) short Plds[4][512];  // per-wave P tile: [q][32 keys]
  short* myP = &Plds[wave][0];
  const short* qbase = hq + ((size_t)b * ML + l16) * DM + wave * HD;
  bf16x8 aq0 = *(const bf16x8*)(qbase + quad * 8);
  bf16x8 aq1 = *(const bf16x8*)(qbase + 32 + quad * 8);
  f32x4 z = {0.f, 0.f, 0.f, 0.f};
  float m_run[4], l_run[4];
  f32x4 O[4];
#pragma unroll
  for (int r = 0; r < 4; r++) { m_run[r] = -1e30f; l_run[r] = 0.f; }
#pragma unroll
  for (int d = 0; d < 4; d++) O[d] = z;
  int j0 = ch * C;
  const float L2E = 1.44269504f;
  for (int jt = 0; jt < C; jt += 32) {
    f32x4 S[2];
#pragma unroll
    for (int tt = 0; tt < 2; tt++) {
      int j = j0 + jt + tt * 16 + l16;
      const short* kb = Kb + ((size_t)b * L + j) * DM + wave * HD;
      bf16x8 b0 = *(const bf16x8*)(kb + quad * 8);
      bf16x8 b1 = *(const bf16x8*)(kb + 32 + quad * 8);
      f32x4 s = MFMA16(aq0, b0, z);
      s = MFMA16(aq1, b1, s);
      int mk = mask[(size_t)b * L + j];
#pragma unroll
      for (int r = 0; r < 4; r++)
        S[tt][r] = mk ? s[r] * 0.125f : -1e30f;
    }
    float p[2][4], alpha[4];
#pragma unroll
    for (int r = 0; r < 4; r++) {
      float v = fmaxf(S[0][r], S[1][r]);
      v = fmaxf(v, __shfl_xor(v, 1, 16));
      v = fmaxf(v, __shfl_xor(v, 2, 16));
      v = fmaxf(v, __shfl_xor(v, 4, 16));
      v = fmaxf(v, __shfl_xor(v, 8, 16));
      float nm = fmaxf(m_run[r], v);
      alpha[r] = exp2f((m_run[r] - nm) * L2E);
      m_run[r] = nm;
      p[0][r] = exp2f((S[0][r] - nm) * L2E);
      p[1][r] = exp2f((S[1][r] - nm) * L2E);
      float ps = p[0][r] + p[1][r];
      ps += __shfl_xor(ps, 1, 16);
      ps += __shfl_xor(ps, 2, 16);
      ps += __shfl_xor(ps, 4, 16);
      ps += __shfl_xor(ps, 8, 16);
      l_run[r] = l_run[r] * alpha[r] + ps;
    }
#pragma unroll
    for (int d = 0; d < 4; d++)
#pragma unroll
      for (int r = 0; r < 4; r++) O[d][r] *= alpha[r];
#pragma unroll
    for (int tt = 0; tt < 2; tt++)
#pragma unroll
      for (int r = 0; r < 4; r++)
        myP[(quad * 4 + r) * 32 + tt * 16 + l16] = f2bf(p[tt][r]);
    __syncthreads();  // P visible (uniform trip count)
    bf16x8 ap = *(const bf16x8*)(myP + l16 * 32 + quad * 8);
#pragma unroll
    for (int d = 0; d < 4; d++) {
      const short* vb = Vt + ((size_t)b * DM + wave * HD + d * 16 + l16) * L + j0 + jt + quad * 8;
      bf16x8 bv = *(const bf16x8*)vb;
      O[d] = MFMA16(ap, bv, O[d]);
    }
    __syncthreads();  // protect P tile
  }
  size_t base = (((size_t)b * NCH + ch) * NH + wave) * ML;
  if (l16 == 0) {
#pragma unroll
    for (int r = 0; r < 4; r++) {
      pm[base + quad * 4 + r] = m_run[r];
      pl[base + quad * 4 + r] = l_run[r];
    }
  }
#pragma unroll
  for (int d = 0; d < 4; d++)
#pragma unroll
    for (int r = 0; r < 4; r++)
      pO[(base + quad * 4 + r) * 64 + d * 16 + l16] = O[d][r];
}

// ---------------- reduce partials + Wo + gate + (next Wq | final out), per batch ----------------
__global__ __launch_bounds__(256, 2) void epilogue(
    const float* __restrict__ pm, const float* __restrict__ pl,
    const float* __restrict__ pO, int NCH,
    float* __restrict__ mem, const short* __restrict__ WoT,
    const short* __restrict__ WgT, const short* __restrict__ bg,
    const short* __restrict__ WqT, short* __restrict__ hq,
    void* __restrict__ outb, const int* __restrict__ flag) {
  int b = blockIdx.x, t = threadIdx.x;
  int isf = flag[0];
  __shared__ float w_lds[NCH_MAX * 64];
  __shared__ float invL[64];
  __shared__ __align__(16) short vec_bf[ML * DM];
  __shared__ __align__(16) short mem_bf[ML * DM];
  __shared__ __align__(16) short attn_bf[ML * DM];
  __shared__ float attn_f[ML * DM];
  __shared__ __align__(16) short memn_bf[ML * DM];

  for (int idx = t; idx < ML * DM; idx += 256)
    mem_bf[idx] = f2bf(mem[(size_t)b * ML * DM + idx]);
  if (t < 64) {  // t = n*16 + i
    size_t base = (size_t)b * NCH * NH * ML + t;
    float M = -1e30f;
    for (int ch = 0; ch < NCH; ch++)
      M = fmaxf(M, pm[base + (size_t)ch * NH * ML]);
    float Ls = 0.f;
    for (int ch = 0; ch < NCH; ch++) {
      float w = exp2f((pm[base + (size_t)ch * NH * ML] - M) * 1.44269504f);
      w_lds[ch * 64 + t] = w;
      Ls += w * pl[base + (size_t)ch * NH * ML];
    }
    invL[t] = 1.0f / Ls;
  }
  __syncthreads();
  {
    int n = t >> 6, d = t & 63;
    for (int i = 0; i < 16; i++) {
      size_t pb = ((size_t)b * NCH * NH * ML + n * ML + i) * 64 + d;
      float o = 0.f;
      for (int ch = 0; ch < NCH; ch++)
        o += w_lds[ch * 64 + n * 16 + i] * pO[pb + (size_t)ch * NH * ML * 64];
      vec_bf[i * DM + n * 64 + d] = f2bf(o * invL[n * 16 + i]);
    }
  }
  __syncthreads();
  int wave = t >> 6, lane = t & 63, quad = lane >> 4, l16 = lane & 15;
  f32x4 z = {0.f, 0.f, 0.f, 0.f};
  f32x4 acc[4];
#pragma unroll
  for (int c = 0; c < 4; c++) acc[c] = z;
#pragma unroll
  for (int kk = 0; kk < 8; kk++) {
    bf16x8 a = *(const bf16x8*)(vec_bf + l16 * DM + kk * 32 + quad * 8);
#pragma unroll
    for (int ct = 0; ct < 4; ct++) {
      const short* wb = WoT + (size_t)(wave * 64 + ct * 16 + l16) * DM + kk * 32 + quad * 8;
      acc[ct] = MFMA16(a, *(const bf16x8*)wb, acc[ct]);
    }
  }
#pragma unroll
  for (int ct = 0; ct < 4; ct++)
#pragma unroll
    for (int r = 0; r < 4; r++) {
      int row = quad * 4 + r, col = wave * 64 + ct * 16 + l16;
      attn_f[row * DM + col] = acc[ct][r];
      attn_bf[row * DM + col] = f2bf(acc[ct][r]);
    }
  __syncthreads();
  f32x4 g[4];
#pragma unroll
  for (int c = 0; c < 4; c++) g[c] = z;
#pragma unroll
  for (int kk = 0; kk < 16; kk++) {
    bf16x8 a = (kk < 8)
        ? *(const bf16x8*)(mem_bf + l16 * DM + kk * 32 + quad * 8)
        : *(const bf16x8*)(attn_bf + l16 * DM + (kk - 8) * 32 + quad * 8);
#pragma unroll
    for (int ct = 0; ct < 4; ct++) {
      const short* wb = WgT + (size_t)(wave * 64 + ct * 16 + l16) * 512 + kk * 32 + quad * 8;
      g[ct] = MFMA16(a, *(const bf16x8*)wb, g[ct]);
    }
  }
#pragma unroll
  for (int ct = 0; ct < 4; ct++)
#pragma unroll
    for (int r = 0; r < 4; r++) {
      int row = quad * 4 + r, col = wave * 64 + ct * 16 + l16;
      float x = g[ct][r] + bf2f(bg[col]);
      float gg = 1.0f / (1.0f + exp2f(-x * 1.44269504f));
      float old = mem[(size_t)b * ML * DM + row * DM + col];
      float mn = gg * old + (1.0f - gg) * attn_f[row * DM + col];
      mem[(size_t)b * ML * DM + row * DM + col] = mn;
      memn_bf[row * DM + col] = f2bf(mn);
      if (outb) {
        size_t oi = (size_t)b * ML * DM + row * DM + col;
        if (isf) ((float*)outb)[oi] = mn;
        else ((short*)outb)[oi] = f2bf(mn);
      }
    }
  __syncthreads();
  if (WqT) {
    f32x4 h[4];
#pragma unroll
    for (int c = 0; c < 4; c++) h[c] = z;
#pragma unroll
    for (int kk = 0; kk < 8; kk++) {
      bf16x8 a = *(const bf16x8*)(memn_bf + l16 * DM + kk * 32 + quad * 8);
#pragma unroll
      for (int ct = 0; ct < 4; ct++) {
        const short* wb = WqT + (size_t)(wave * 64 + ct * 16 + l16) * DM + kk * 32 + quad * 8;
        h[ct] = MFMA16(a, *(const bf16x8*)wb, h[ct]);
      }
    }
#pragma unroll
    for (int ct = 0; ct < 4; ct++)
#pragma unroll
      for (int r = 0; r < 4; r++)
        hq[(size_t)b * ML * DM + (quad * 4 + r) * DM + wave * 64 + ct * 16 + l16] = f2bf(h[ct][r]);
  }
}

// ---------------- launch ----------------
extern "C" void kernel_launch(void* const* d_in, const int* in_sizes, int n_in,
                              void* d_out, int out_size, void* d_ws, size_t ws_size,
                              hipStream_t stream) {
  const void* pattern = d_in[0];
  const void* graph = d_in[1];
  const int* pmask = (const int*)d_in[2];
  const int* gmask = (const int*)d_in[3];

  char* ws = (char*)d_ws;
  size_t off = 0;
  auto alloc = [&](size_t bytes) {
    void* p = ws + off;
    off = (off + bytes + 255) & ~(size_t)255;
    return p;
  };
  int* flag = (int*)alloc(4);
  // WT order: 0 pWqT 1 pWkT 2 pWvT 3 pWoT 4 pWgT 5 gWqT 6 gWkT 7 gWvT 8 gWoT 9 gWgT
  int rows[10] = {256, 256, 256, 256, 512, 256, 256, 256, 256, 512};
  int srcidx[10] = {4, 5, 6, 7, 8, 10, 11, 12, 13, 14};
  short* WT[10];
  for (int i = 0; i < 10; i++) WT[i] = (short*)alloc((size_t)rows[i] * 256 * 2);
  short* bgc = (short*)alloc(512 * 2);  // [p_bg(256), g_bg(256)]
  short* Kp = (short*)alloc((size_t)BB * PLEN * DM * 2);
  short* Vpt = (short*)alloc((size_t)BB * PLEN * DM * 2);
  short* Kg = (short*)alloc((size_t)BB * GLEN * DM * 2);
  short* Vgt = (short*)alloc((size_t)BB * GLEN * DM * 2);
  short* hq = (short*)alloc((size_t)BB * ML * DM * 2);
  float* memf = (float*)alloc((size_t)BB * ML * DM * 4);
  float* pm = (float*)alloc((size_t)BB * NCH_MAX * NH * ML * 4);
  float* pl = (float*)alloc((size_t)BB * NCH_MAX * NH * ML * 4);
  float* pO = (float*)alloc((size_t)BB * NCH_MAX * NH * ML * 64 * 4);
  float* partG = (float*)alloc((size_t)(BB * GLEN / 128) * 256 * 4);  // 2 MB
  short* gbf = (short*)alloc((size_t)BB * GLEN * DM * 2);             // 134 MB
  short* pbf = (short*)alloc((size_t)BB * PLEN * DM * 2);             // 4 MB
  if (off > ws_size) return;  // ws too small: output stays zero -> diagnostic signal

  detect_dtype<<<dim3(1), dim3(256), 0, stream>>>((const short*)pattern, flag);

  WTArgs wa;
  for (int i = 0; i < 10; i++) {
    wa.src[i] = d_in[srcidx[i]];
    wa.dst[i] = WT[i];
    wa.rows[i] = rows[i];
  }
  transpose_w<<<dim3(16, 8, 10), dim3(32, 8), 0, stream>>>(wa, flag);
  conv_bias<<<dim3(1), dim3(256), 0, stream>>>(d_in[9], d_in[15], bgc, flag);

  convert_sum<<<dim3(BB * GLEN / 128), dim3(256), 0, stream>>>(graph, gbf, partG, flag, 1);
  convert_sum<<<dim3(BB * PLEN / 128), dim3(256), 0, stream>>>(pattern, pbf, (float*)nullptr, flag, 0);
  finalize_q0<<<dim3(BB * ML), dim3(256), 0, stream>>>(partG, d_in[4], memf, hq, flag);

  proj_kv<<<dim3(BB * PLEN / 128, 2), dim3(512), 0, stream>>>(pbf, WT[1], WT[2], Kp, Vpt, PLEN);
  proj_kv<<<dim3(BB * GLEN / 128, 2), dim3(512), 0, stream>>>(gbf, WT[6], WT[7], Kg, Vgt, GLEN);

  for (int s = 0; s < 3; s++) {
    // pattern attention
    flash_partial<<<dim3(8, BB), dim3(256), 0, stream>>>(hq, Kp, Vpt, pmask, pm, pl, pO, PLEN, 8);
    epilogue<<<dim3(BB), dim3(256), 0, stream>>>(pm, pl, pO, 8, memf, WT[3], WT[4], bgc,
                                                 (const short*)WT[5], hq, (void*)nullptr, flag);
    // graph attention
    bool last = (s == 2);
    flash_partial<<<dim3(32, BB), dim3(256), 0, stream>>>(hq, Kg, Vgt, gmask, pm, pl, pO, GLEN, 32);
    epilogue<<<dim3(BB), dim3(256), 0, stream>>>(pm, pl, pO, 32, memf, WT[8], WT[9], bgc + 256,
                                                 last ? (const short*)nullptr : (const short*)WT[0],
                                                 hq, last ? d_out : (void*)nullptr, flag);
  }
}